// Round 11
// baseline (156.207 us; speedup 1.0000x reference)
//
#include <hip/hip_runtime.h>
#include <hip/hip_bf16.h>

// B=4, T=2048, C=1024, D=64 ; causal single-head attention, fp32 in/out.
constexpr int Bn = 4;
constexpr int Tn = 2048;
constexpr int Cn = 1024;
constexpr int Dn = 64;

typedef __attribute__((ext_vector_type(8))) short short8;  // 8 bf16 (4 VGPRs)
typedef __attribute__((ext_vector_type(4))) float f32x4;   // MFMA acc

// fp32 -> bf16 bits, round-to-nearest-even
__device__ inline short f2bf(float f) {
    unsigned u = __builtin_bit_cast(unsigned, f);
    u += 0x7FFFu + ((u >> 16) & 1u);
    return (short)(u >> 16);
}

// ---------------------------------------------------------------------------
// Kernel 0: prep.  Blocks [0,48): weights -> bf16 transposed wt[sel][n][k].
// Blocks [48,1072): x -> bf16 (one-time convert; removes per-iter f2bf from
// the qkv hot loop and cuts its global read traffic 96 MB fp32 -> 16 MB bf16).
// ---------------------------------------------------------------------------
__global__ __launch_bounds__(256) void prep(
    const float* __restrict__ x,
    const float* __restrict__ wq, const float* __restrict__ wk,
    const float* __restrict__ wv,
    short* __restrict__ wt, short* __restrict__ xbf)
{
    if (blockIdx.x < 48) {
        const int sel = blockIdx.x >> 4;
        const float* w = sel == 0 ? wq : (sel == 1 ? wk : wv);
        short* o = wt + (size_t)sel * Dn * Cn;
        const int base = (blockIdx.x & 15) * 4096;
        for (int idx = base + threadIdx.x; idx < base + 4096; idx += 256) {
            int n = idx >> 10, k = idx & 1023;     // write o[n][k] coalesced
            o[idx] = f2bf(w[k * Dn + n]);
        }
    } else {
        const int idx = (blockIdx.x - 48) * 256 + threadIdx.x;  // 262144 threads
        const float4* xf = reinterpret_cast<const float4*>(x);
        short8* xo = reinterpret_cast<short8*>(xbf);
        constexpr int NU = Bn * Tn * Cn / 8;       // 1048576 short8 units
        for (int u = idx; u < NU; u += 262144) {
            float4 a = xf[2 * u], c = xf[2 * u + 1];
            short8 o;
            o[0] = f2bf(a.x); o[1] = f2bf(a.y); o[2] = f2bf(a.z); o[3] = f2bf(a.w);
            o[4] = f2bf(c.x); o[5] = f2bf(c.y); o[6] = f2bf(c.z); o[7] = f2bf(c.w);
            xo[u] = o;
        }
    }
}

// ---------------------------------------------------------------------------
// Kernel 1: QKV projection via bf16 MFMA.  Grid (512, 3, 2): y = sel,
// z = n-half.  One wave per block: 16 rows x 32 cols, K-loop = 3 bf16 loads
// + 2 MFMA per iter (3072 waves = 3/SIMD; round-9 had 1536 = 1.5/SIMD).
// Fragment convention (consistent A/B => k-permutation cancels):
//   A slot(lane,j) = A[lane&15][8*(lane>>4)+j], B slot = B[8*(lane>>4)+j][lane&15]
//   C/D (verified, m89): row=(lane>>4)*4+reg, col=lane&15
// ---------------------------------------------------------------------------
__global__ __launch_bounds__(64) void qkv_mfma(
    const short* __restrict__ xbf, const short* __restrict__ wt,
    const float* __restrict__ bq, const float* __restrict__ bk,
    const float* __restrict__ bv,
    short* __restrict__ Qbf, short* __restrict__ Kbf, short* __restrict__ Vt)
{
    const int l = threadIdx.x;
    const int i = l & 15, g = l >> 4;
    const int rowbase = blockIdx.x * 16;
    const int sel = blockIdx.y;
    const int nh = blockIdx.z;                     // n-half: cols [32nh, 32nh+32)

    const short* ws   = wt + (size_t)sel * Dn * Cn;
    const float* bias = sel == 0 ? bq : (sel == 1 ? bk : bv);

    f32x4 acc[2];
    #pragma unroll
    for (int nt2 = 0; nt2 < 2; ++nt2)
        #pragma unroll
        for (int r = 0; r < 4; ++r) acc[nt2][r] = 0.f;

    const short* xrow = xbf + (size_t)(rowbase + i) * Cn + 8 * g;  // A row = lane&15
    const short* wb0  = ws + (size_t)(nh * 32 + i) * Cn + 8 * g;
    const short* wb1  = wb0 + (size_t)16 * Cn;

    for (int k0 = 0; k0 < Cn; k0 += 32) {
        short8 af = *reinterpret_cast<const short8*>(xrow + k0);
        short8 b0 = *reinterpret_cast<const short8*>(wb0 + k0);
        short8 b1 = *reinterpret_cast<const short8*>(wb1 + k0);
        acc[0] = __builtin_amdgcn_mfma_f32_16x16x32_bf16(af, b0, acc[0], 0, 0, 0);
        acc[1] = __builtin_amdgcn_mfma_f32_16x16x32_bf16(af, b1, acc[1], 0, 0, 0);
    }

    #pragma unroll
    for (int r = 0; r < 4; ++r) {
        const int rho = rowbase + 4 * g + r;          // C/D row
        const int b = rho >> 11, t = rho & (Tn - 1);
        #pragma unroll
        for (int nt2 = 0; nt2 < 2; ++nt2) {
            const int n = (nh * 2 + nt2) * 16 + i;    // C/D col
            const float val = acc[nt2][r] + bias[n];
            if (sel == 0)      Qbf[(size_t)rho * Dn + n] = f2bf(val * 0.125f);
            else if (sel == 1) Kbf[(size_t)rho * Dn + n] = f2bf(val);
            else               Vt[((size_t)b * Dn + n) * Tn + t] = f2bf(val);
        }
    }
}

// ---------------------------------------------------------------------------
// Kernel 2: fused causal flash attention, KV-SPLIT ACROSS 8 WAVES.
// Grid (T/16, B), block = 8 waves.  Wave w handles chunks kb ≡ w (mod 8)
// with an independent online softmax; partials merge via LDS + one barrier:
//   M = max m_p ; L = Σ l_p e^{m_p-M} ; O = Σ O_p e^{m_p-M} ; out = O/L.
// 4096 waves (4/SIMD); critical path <= ceil(32/8) = 4 chunks.
// ---------------------------------------------------------------------------
__global__ __launch_bounds__(512) void attn_fused(
    const short* __restrict__ Qbf, const short* __restrict__ Kbf,
    const short* __restrict__ Vt, float* __restrict__ out)
{
    __shared__ __align__(16) short Plds[8][16][72];
    __shared__ float o_part[8][16][68];               // pad 68: bank-spread
    __shared__ float ml_part[8][2][16];               // [w][0]=m, [w][1]=l

    const int tid = threadIdx.x;
    const int w = tid >> 6, l = tid & 63;
    const int i = l & 15, g = l >> 4;
    const int b = blockIdx.y;
    const int qw = blockIdx.x * 16;                   // block's 16 q-rows

    const short* Qb = Qbf + (size_t)b * Tn * Dn;
    const short* Kb = Kbf + (size_t)b * Tn * Dn;
    const short* Vb = Vt + (size_t)b * Dn * Tn;

    // Q fragments (A row = lane&15), shared by all waves (L1 broadcast)
    short8 qf0 = *reinterpret_cast<const short8*>(Qb + (size_t)(qw + i) * Dn + 8 * g);
    short8 qf1 = *reinterpret_cast<const short8*>(Qb + (size_t)(qw + i) * Dn + 32 + 8 * g);

    f32x4 o4[4];
    f32x4 m, lsum;
    #pragma unroll
    for (int r = 0; r < 4; ++r) { m[r] = -1e30f; lsum[r] = 0.f; }
    #pragma unroll
    for (int dt = 0; dt < 4; ++dt)
        #pragma unroll
        for (int r = 0; r < 4; ++r) o4[dt][r] = 0.f;

    const int nch = (qw + 79) >> 6;                   // chunks covering keys <= qw+15
    for (int kb = w; kb < nch; kb += 8) {
        const int K0 = kb * 64;

        // ---- S = Q K^T ----
        f32x4 s[4];
        #pragma unroll
        for (int nt = 0; nt < 4; ++nt)
            #pragma unroll
            for (int r = 0; r < 4; ++r) s[nt][r] = 0.f;
        #pragma unroll
        for (int nt = 0; nt < 4; ++nt) {
            const short* kr = Kb + (size_t)(K0 + nt * 16 + i) * Dn + 8 * g;
            short8 kf0 = *reinterpret_cast<const short8*>(kr);
            short8 kf1 = *reinterpret_cast<const short8*>(kr + 32);
            s[nt] = __builtin_amdgcn_mfma_f32_16x16x32_bf16(qf0, kf0, s[nt], 0, 0, 0);
            s[nt] = __builtin_amdgcn_mfma_f32_16x16x32_bf16(qf1, kf1, s[nt], 0, 0, 0);
        }

        // ---- causal mask (only near the diagonal) ----
        if (K0 + 63 > qw) {
            #pragma unroll
            for (int nt = 0; nt < 4; ++nt)
                #pragma unroll
                for (int r = 0; r < 4; ++r) {
                    if (K0 + nt * 16 + i > qw + 4 * g + r) s[nt][r] = -1e30f;
                }
        }

        // ---- online softmax over this wave's chunks ----
        f32x4 rm;
        #pragma unroll
        for (int r = 0; r < 4; ++r)
            rm[r] = fmaxf(fmaxf(s[0][r], s[1][r]), fmaxf(s[2][r], s[3][r]));
        #pragma unroll
        for (int msk = 1; msk < 16; msk <<= 1)
            #pragma unroll
            for (int r = 0; r < 4; ++r) rm[r] = fmaxf(rm[r], __shfl_xor(rm[r], msk));

        f32x4 scl;
        #pragma unroll
        for (int r = 0; r < 4; ++r) {
            float mn = fmaxf(m[r], rm[r]);
            scl[r] = __expf(m[r] - mn);
            m[r] = mn;
            lsum[r] *= scl[r];
        }
        #pragma unroll
        for (int dt = 0; dt < 4; ++dt)
            #pragma unroll
            for (int r = 0; r < 4; ++r) o4[dt][r] *= scl[r];

        f32x4 rs;
        #pragma unroll
        for (int r = 0; r < 4; ++r) rs[r] = 0.f;
        #pragma unroll
        for (int nt = 0; nt < 4; ++nt)
            #pragma unroll
            for (int r = 0; r < 4; ++r) {
                float p = __expf(s[nt][r] - m[r]);
                rs[r] += p;
                Plds[w][4 * g + r][nt * 16 + i] = f2bf(p);
            }
        #pragma unroll
        for (int msk = 1; msk < 16; msk <<= 1)
            #pragma unroll
            for (int r = 0; r < 4; ++r) rs[r] += __shfl_xor(rs[r], msk);
        #pragma unroll
        for (int r = 0; r < 4; ++r) lsum[r] += rs[r];

        // wave-private LDS roundtrip: drain own writes, pin ordering
        asm volatile("s_waitcnt lgkmcnt(0)" ::: "memory");
        __builtin_amdgcn_sched_barrier(0);

        // ---- O += P V ----
        short8 pf0 = *reinterpret_cast<const short8*>(&Plds[w][i][8 * g]);
        short8 pf1 = *reinterpret_cast<const short8*>(&Plds[w][i][32 + 8 * g]);
        #pragma unroll
        for (int dt = 0; dt < 4; ++dt) {
            const short* vr = Vb + (size_t)(dt * 16 + i) * Tn + K0 + 8 * g;
            short8 vf0 = *reinterpret_cast<const short8*>(vr);
            short8 vf1 = *reinterpret_cast<const short8*>(vr + 32);
            o4[dt] = __builtin_amdgcn_mfma_f32_16x16x32_bf16(pf0, vf0, o4[dt], 0, 0, 0);
            o4[dt] = __builtin_amdgcn_mfma_f32_16x16x32_bf16(pf1, vf1, o4[dt], 0, 0, 0);
        }
    }

    // ---- publish partials ----
    #pragma unroll
    for (int dt = 0; dt < 4; ++dt)
        #pragma unroll
        for (int r = 0; r < 4; ++r)
            o_part[w][4 * g + r][dt * 16 + i] = o4[dt][r];
    if (i == 0) {
        #pragma unroll
        for (int r = 0; r < 4; ++r) {
            ml_part[w][0][4 * g + r] = m[r];
            ml_part[w][1][4 * g + r] = lsum[r];
        }
    }
    __syncthreads();

    // ---- merge: waves 0-3 own output cols [16w, 16w+16), rows 4g+r ----
    if (w < 4) {
        #pragma unroll
        for (int r = 0; r < 4; ++r) {
            const int row = 4 * g + r;
            float M = -1e30f;
            #pragma unroll
            for (int p = 0; p < 8; ++p) M = fmaxf(M, ml_part[p][0][row]);
            float L = 0.f, O = 0.f;
            #pragma unroll
            for (int p = 0; p < 8; ++p) {
                float wp = __expf(ml_part[p][0][row] - M);
                L += ml_part[p][1][row] * wp;
                O += o_part[p][row][w * 16 + i] * wp;
            }
            out[((size_t)b * Tn + qw + row) * Dn + w * 16 + i] = O / L;
        }
    }
}

// ---------------------------------------------------------------------------
extern "C" void kernel_launch(void* const* d_in, const int* in_sizes, int n_in,
                              void* d_out, int out_size, void* d_ws, size_t ws_size,
                              hipStream_t stream) {
    const float* x  = (const float*)d_in[0];
    const float* wq = (const float*)d_in[1];
    const float* wk = (const float*)d_in[2];
    const float* wv = (const float*)d_in[3];
    const float* bq = (const float*)d_in[4];
    const float* bk = (const float*)d_in[5];
    const float* bv = (const float*)d_in[6];
    float* out = (float*)d_out;

    short* wt  = (short*)d_ws;                       // 3*64*1024  bf16
    short* xbf = wt + 3 * Dn * Cn;                   // 4*2048*1024 bf16 (16 MB)
    short* Qbf = xbf + (size_t)Bn * Tn * Cn;         // 4*2048*64  bf16 each
    short* Kbf = Qbf + (size_t)Bn * Tn * Dn;
    short* Vt  = Kbf + (size_t)Bn * Tn * Dn;         // transposed (b,d,t)

    prep<<<1072, 256, 0, stream>>>(x, wq, wk, wv, wt, xbf);
    qkv_mfma<<<dim3((Bn * Tn) / 16, 3, 2), 64, 0, stream>>>(
        xbf, wt, bq, bk, bv, Qbf, Kbf, Vt);
    attn_fused<<<dim3(Tn / 16, Bn), 512, 0, stream>>>(Qbf, Kbf, Vt, out);
}

// Round 12
// 149.431 us; speedup vs baseline: 1.0453x; 1.0453x over previous
//
#include <hip/hip_runtime.h>
#include <hip/hip_bf16.h>

// B=4, T=2048, C=1024, D=64 ; causal single-head attention, fp32 in/out.
constexpr int Bn = 4;
constexpr int Tn = 2048;
constexpr int Cn = 1024;
constexpr int Dn = 64;

typedef __attribute__((ext_vector_type(8))) short short8;  // 8 bf16 (4 VGPRs)
typedef __attribute__((ext_vector_type(4))) float f32x4;   // MFMA acc

// fp32 -> bf16 bits, round-to-nearest-even
__device__ inline short f2bf(float f) {
    unsigned u = __builtin_bit_cast(unsigned, f);
    u += 0x7FFFu + ((u >> 16) & 1u);
    return (short)(u >> 16);
}

// ---------------------------------------------------------------------------
// Kernel 0: weights -> bf16, transposed: wt[sel][n=0..63][k=0..1023]
// (x-prep pass from round 11 removed: its 48 MB + launch cost ≥ its benefit.)
// ---------------------------------------------------------------------------
__global__ __launch_bounds__(256) void prep_w(
    const float* __restrict__ wq, const float* __restrict__ wk,
    const float* __restrict__ wv, short* __restrict__ wt)
{
    const int sel = blockIdx.x >> 4;           // 48 blocks: 3 sel x 16 parts
    const float* w = sel == 0 ? wq : (sel == 1 ? wk : wv);
    short* o = wt + (size_t)sel * Dn * Cn;
    const int base = (blockIdx.x & 15) * 4096;
    for (int idx = base + threadIdx.x; idx < base + 4096; idx += 256) {
        int n = idx >> 10, k = idx & 1023;     // write o[n][k] coalesced
        o[idx] = f2bf(w[k * Dn + n]);
    }
}

// ---------------------------------------------------------------------------
// Kernel 1: QKV projection via bf16 MFMA.  Grid (512, 3): y = sel, one wave
// per block, 16 rows x 64 cols, 4 independent MFMA chains.  Round-9 version
// showed VGPR=44 => compiler did NOT pipeline the 32-iter K loop; this adds
// an explicit depth-2 x-prefetch ring (fully unrolled so ring indices are
// compile-time constants -- rule #20).  x read as fp32 (L3-resident for the
// 2nd/3rd sel pass), converted inline.
// ---------------------------------------------------------------------------
__global__ __launch_bounds__(64) void qkv_mfma(
    const float* __restrict__ x, const short* __restrict__ wt,
    const float* __restrict__ bq, const float* __restrict__ bk,
    const float* __restrict__ bv,
    short* __restrict__ Qbf, short* __restrict__ Kbf, short* __restrict__ Vt)
{
    const int l = threadIdx.x;
    const int i = l & 15, g = l >> 4;
    const int rowbase = blockIdx.x * 16;
    const int sel = blockIdx.y;

    const short* ws   = wt + (size_t)sel * Dn * Cn;
    const float* bias = sel == 0 ? bq : (sel == 1 ? bk : bv);

    f32x4 acc[4];
    #pragma unroll
    for (int nt = 0; nt < 4; ++nt)
        #pragma unroll
        for (int r = 0; r < 4; ++r) acc[nt][r] = 0.f;

    const float* xrow = x + (size_t)(rowbase + i) * Cn + 8 * g;  // A row = lane&15

    // depth-2 prefetch ring for the x fragment (2 float4 per K-step)
    float4 pa[2], pb[2];
    pa[0] = *reinterpret_cast<const float4*>(xrow + 0);
    pb[0] = *reinterpret_cast<const float4*>(xrow + 4);
    pa[1] = *reinterpret_cast<const float4*>(xrow + 32);
    pb[1] = *reinterpret_cast<const float4*>(xrow + 36);

    #pragma unroll
    for (int k0 = 0; k0 < Cn; k0 += 32) {
        const int s = (k0 >> 5) & 1;               // compile-time after unroll
        float4 x0 = pa[s], x1 = pb[s];
        const int kn = k0 + 64;
        if (kn < Cn) {
            pa[s] = *reinterpret_cast<const float4*>(xrow + kn);
            pb[s] = *reinterpret_cast<const float4*>(xrow + kn + 4);
        }
        short8 af;
        af[0] = f2bf(x0.x); af[1] = f2bf(x0.y); af[2] = f2bf(x0.z); af[3] = f2bf(x0.w);
        af[4] = f2bf(x1.x); af[5] = f2bf(x1.y); af[6] = f2bf(x1.z); af[7] = f2bf(x1.w);
        #pragma unroll
        for (int nt = 0; nt < 4; ++nt) {
            short8 bf = *reinterpret_cast<const short8*>(
                ws + (size_t)(nt * 16 + i) * Cn + k0 + 8 * g);
            acc[nt] = __builtin_amdgcn_mfma_f32_16x16x32_bf16(af, bf, acc[nt], 0, 0, 0);
        }
    }

    #pragma unroll
    for (int r = 0; r < 4; ++r) {
        const int rho = rowbase + 4 * g + r;          // C/D row
        const int b = rho >> 11, t = rho & (Tn - 1);
        #pragma unroll
        for (int nt = 0; nt < 4; ++nt) {
            const int n = nt * 16 + i;                // C/D col
            const float val = acc[nt][r] + bias[n];
            if (sel == 0)      Qbf[(size_t)rho * Dn + n] = f2bf(val * 0.125f);
            else if (sel == 1) Kbf[(size_t)rho * Dn + n] = f2bf(val);
            else               Vt[((size_t)b * Dn + n) * Tn + t] = f2bf(val);
        }
    }
}

// ---------------------------------------------------------------------------
// Kernel 2: fused causal flash attention, KV-split across 8 waves (round-11
// structure) + V-LOAD HOIST: V fragments issue right after QK^T, before the
// softmax VALU section, so their ~300cy latency hides under softmax instead
// of being pinned below the sched_barrier (T14 issue-early/use-late).
// ---------------------------------------------------------------------------
__global__ __launch_bounds__(512) void attn_fused(
    const short* __restrict__ Qbf, const short* __restrict__ Kbf,
    const short* __restrict__ Vt, float* __restrict__ out)
{
    __shared__ __align__(16) short Plds[8][16][72];
    __shared__ float o_part[8][16][68];
    __shared__ float ml_part[8][2][16];

    const int tid = threadIdx.x;
    const int w = tid >> 6, l = tid & 63;
    const int i = l & 15, g = l >> 4;
    const int b = blockIdx.y;
    const int qw = blockIdx.x * 16;

    const short* Qb = Qbf + (size_t)b * Tn * Dn;
    const short* Kb = Kbf + (size_t)b * Tn * Dn;
    const short* Vb = Vt + (size_t)b * Dn * Tn;

    short8 qf0 = *reinterpret_cast<const short8*>(Qb + (size_t)(qw + i) * Dn + 8 * g);
    short8 qf1 = *reinterpret_cast<const short8*>(Qb + (size_t)(qw + i) * Dn + 32 + 8 * g);

    f32x4 o4[4];
    f32x4 m, lsum;
    #pragma unroll
    for (int r = 0; r < 4; ++r) { m[r] = -1e30f; lsum[r] = 0.f; }
    #pragma unroll
    for (int dt = 0; dt < 4; ++dt)
        #pragma unroll
        for (int r = 0; r < 4; ++r) o4[dt][r] = 0.f;

    const int nch = (qw + 79) >> 6;
    for (int kb = w; kb < nch; kb += 8) {
        const int K0 = kb * 64;

        // ---- S = Q K^T ----
        f32x4 s[4];
        #pragma unroll
        for (int nt = 0; nt < 4; ++nt)
            #pragma unroll
            for (int r = 0; r < 4; ++r) s[nt][r] = 0.f;
        #pragma unroll
        for (int nt = 0; nt < 4; ++nt) {
            const short* kr = Kb + (size_t)(K0 + nt * 16 + i) * Dn + 8 * g;
            short8 kf0 = *reinterpret_cast<const short8*>(kr);
            short8 kf1 = *reinterpret_cast<const short8*>(kr + 32);
            s[nt] = __builtin_amdgcn_mfma_f32_16x16x32_bf16(qf0, kf0, s[nt], 0, 0, 0);
            s[nt] = __builtin_amdgcn_mfma_f32_16x16x32_bf16(qf1, kf1, s[nt], 0, 0, 0);
        }

        // ---- V-load hoist: issue now, consume after the barrier ----
        short8 vf0[4], vf1[4];
        #pragma unroll
        for (int dt = 0; dt < 4; ++dt) {
            const short* vr = Vb + (size_t)(dt * 16 + i) * Tn + K0 + 8 * g;
            vf0[dt] = *reinterpret_cast<const short8*>(vr);
            vf1[dt] = *reinterpret_cast<const short8*>(vr + 32);
        }

        // ---- causal mask (only near the diagonal) ----
        if (K0 + 63 > qw) {
            #pragma unroll
            for (int nt = 0; nt < 4; ++nt)
                #pragma unroll
                for (int r = 0; r < 4; ++r) {
                    if (K0 + nt * 16 + i > qw + 4 * g + r) s[nt][r] = -1e30f;
                }
        }

        // ---- online softmax over this wave's chunks ----
        f32x4 rm;
        #pragma unroll
        for (int r = 0; r < 4; ++r)
            rm[r] = fmaxf(fmaxf(s[0][r], s[1][r]), fmaxf(s[2][r], s[3][r]));
        #pragma unroll
        for (int msk = 1; msk < 16; msk <<= 1)
            #pragma unroll
            for (int r = 0; r < 4; ++r) rm[r] = fmaxf(rm[r], __shfl_xor(rm[r], msk));

        f32x4 scl;
        #pragma unroll
        for (int r = 0; r < 4; ++r) {
            float mn = fmaxf(m[r], rm[r]);
            scl[r] = __expf(m[r] - mn);
            m[r] = mn;
            lsum[r] *= scl[r];
        }
        #pragma unroll
        for (int dt = 0; dt < 4; ++dt)
            #pragma unroll
            for (int r = 0; r < 4; ++r) o4[dt][r] *= scl[r];

        f32x4 rs;
        #pragma unroll
        for (int r = 0; r < 4; ++r) rs[r] = 0.f;
        #pragma unroll
        for (int nt = 0; nt < 4; ++nt)
            #pragma unroll
            for (int r = 0; r < 4; ++r) {
                float p = __expf(s[nt][r] - m[r]);
                rs[r] += p;
                Plds[w][4 * g + r][nt * 16 + i] = f2bf(p);
            }
        #pragma unroll
        for (int msk = 1; msk < 16; msk <<= 1)
            #pragma unroll
            for (int r = 0; r < 4; ++r) rs[r] += __shfl_xor(rs[r], msk);
        #pragma unroll
        for (int r = 0; r < 4; ++r) lsum[r] += rs[r];

        // wave-private LDS roundtrip: drain own writes, pin ordering
        asm volatile("s_waitcnt lgkmcnt(0)" ::: "memory");
        __builtin_amdgcn_sched_barrier(0);

        // ---- O += P V (V already in registers) ----
        short8 pf0 = *reinterpret_cast<const short8*>(&Plds[w][i][8 * g]);
        short8 pf1 = *reinterpret_cast<const short8*>(&Plds[w][i][32 + 8 * g]);
        #pragma unroll
        for (int dt = 0; dt < 4; ++dt) {
            o4[dt] = __builtin_amdgcn_mfma_f32_16x16x32_bf16(pf0, vf0[dt], o4[dt], 0, 0, 0);
            o4[dt] = __builtin_amdgcn_mfma_f32_16x16x32_bf16(pf1, vf1[dt], o4[dt], 0, 0, 0);
        }
    }

    // ---- publish partials ----
    #pragma unroll
    for (int dt = 0; dt < 4; ++dt)
        #pragma unroll
        for (int r = 0; r < 4; ++r)
            o_part[w][4 * g + r][dt * 16 + i] = o4[dt][r];
    if (i == 0) {
        #pragma unroll
        for (int r = 0; r < 4; ++r) {
            ml_part[w][0][4 * g + r] = m[r];
            ml_part[w][1][4 * g + r] = lsum[r];
        }
    }
    __syncthreads();

    // ---- merge: waves 0-3 own output cols [16w, 16w+16) ----
    if (w < 4) {
        #pragma unroll
        for (int r = 0; r < 4; ++r) {
            const int row = 4 * g + r;
            float M = -1e30f;
            #pragma unroll
            for (int p = 0; p < 8; ++p) M = fmaxf(M, ml_part[p][0][row]);
            float L = 0.f, O = 0.f;
            #pragma unroll
            for (int p = 0; p < 8; ++p) {
                float wp = __expf(ml_part[p][0][row] - M);
                L += ml_part[p][1][row] * wp;
                O += o_part[p][row][w * 16 + i] * wp;
            }
            out[((size_t)b * Tn + qw + row) * Dn + w * 16 + i] = O / L;
        }
    }
}

// ---------------------------------------------------------------------------
extern "C" void kernel_launch(void* const* d_in, const int* in_sizes, int n_in,
                              void* d_out, int out_size, void* d_ws, size_t ws_size,
                              hipStream_t stream) {
    const float* x  = (const float*)d_in[0];
    const float* wq = (const float*)d_in[1];
    const float* wk = (const float*)d_in[2];
    const float* wv = (const float*)d_in[3];
    const float* bq = (const float*)d_in[4];
    const float* bk = (const float*)d_in[5];
    const float* bv = (const float*)d_in[6];
    float* out = (float*)d_out;

    short* wt  = (short*)d_ws;                       // 3*64*1024  bf16
    short* Qbf = wt + 3 * Dn * Cn;                   // 4*2048*64  bf16 each
    short* Kbf = Qbf + (size_t)Bn * Tn * Dn;
    short* Vt  = Kbf + (size_t)Bn * Tn * Dn;         // transposed (b,d,t)

    prep_w<<<48, 256, 0, stream>>>(wq, wk, wv, wt);
    qkv_mfma<<<dim3((Bn * Tn) / 16, 3), 64, 0, stream>>>(
        x, wt, bq, bk, bv, Qbf, Kbf, Vt);
    attn_fused<<<dim3(Tn / 16, Bn), 512, 0, stream>>>(Qbf, Kbf, Vt, out);
}